// Round 3
// baseline (1967.201 us; speedup 1.0000x reference)
//
#include <hip/hip_runtime.h>
#include <hip/hip_bf16.h>
#include <math.h>

#define TS 256
#define TILES 8
#define MBLK 128
#define MAXN 192
#define NP 193   // LDS row stride; 193 % 32 == 1 -> conflict-free column reads

typedef __attribute__((ext_vector_type(8))) short bf8;
typedef __attribute__((ext_vector_type(4))) float f32x4;

#define MFMA(a, b, c) __builtin_amdgcn_mfma_f32_16x16x32_bf16(a, b, c, 0, 0, 0)

__device__ __forceinline__ float fast_rcp(float x) { return __builtin_amdgcn_rcpf(x); }
__device__ __forceinline__ float sigm(float x) { return fast_rcp(1.0f + __expf(-x)); }
__device__ __forceinline__ float tanh2(float x) { return fmaf(2.0f, fast_rcp(1.0f + __expf(-2.0f * x)), -1.0f); }

__device__ __forceinline__ unsigned short f2bf(float v) {
    union { __hip_bfloat16 b; unsigned short u; } cv;
    cv.b = __float2bfloat16(v);
    return cv.u;
}
__device__ __forceinline__ float bf2f(unsigned short u) {
    union { unsigned short u; __hip_bfloat16 b; } cv;
    cv.u = u;
    return __bfloat162float(cv.b);
}

// ---------------------------------------------------------------------------
// prep: split-bf16 B-fragments of node weights, f32 transposes of LSTM
// weights, segment starts. (unchanged from round 2)
// ---------------------------------------------------------------------------
__global__ void prep_kernel(const float* __restrict__ l0w, const float* __restrict__ l1w,
                            const float* __restrict__ gwih, const float* __restrict__ gwhh,
                            const float* __restrict__ lwih, const float* __restrict__ lwhh,
                            const int* __restrict__ batch,
                            unsigned short* __restrict__ whi, unsigned short* __restrict__ wlo,
                            float* __restrict__ liT, float* __restrict__ lhT,
                            int* __restrict__ startp,
                            int n_nodes, int n_graphs)
{
    int tid = blockIdx.x * 256 + threadIdx.x;
    if (tid < 32768) {
        int e = tid & 7, lane = (tid >> 3) & 63, ks = (tid >> 9) & 1, jt = tid >> 10;
        const float* W; int jl;
        if (jt < 4)       { W = l0w;  jl = jt; }
        else if (jt < 8)  { W = l1w;  jl = jt - 4; }
        else if (jt < 20) { W = gwih; jl = jt - 8; }
        else              { W = gwhh; jl = jt - 20; }
        int j = jl * 16 + (lane & 15);
        int k = ks * 32 + (lane >> 4) * 8 + e;
        float v = W[j * 64 + k];
        unsigned short hi = f2bf(v);
        whi[tid] = hi;
        wlo[tid] = f2bf(v - bf2f(hi));
    }
    if (tid < 32768) liT[tid] = lwih[(tid & 255) * 128 + (tid >> 8)];
    if (tid < 16384) lhT[tid] = lwhh[(tid & 255) * 64 + (tid >> 8)];
    if (tid <= n_graphs) {
        int lo = 0, hi = n_nodes;
        while (lo < hi) {
            int mid = (lo + hi) >> 1;
            if (batch[mid] < tid) lo = mid + 1; else hi = mid;
        }
        startp[tid] = lo;
    }
}

// ---------------------------------------------------------------------------
// node pipeline via split-bf16 MFMA (unchanged from round 2)
// ---------------------------------------------------------------------------
__launch_bounds__(256, 2)
__global__ void node_kernel(const float* __restrict__ x,
                            const unsigned short* __restrict__ whi,
                            const unsigned short* __restrict__ wlo,
                            const float* __restrict__ l0b, const float* __restrict__ l1b,
                            const float* __restrict__ gbih, const float* __restrict__ gbhh,
                            float* __restrict__ outv, int n_nodes)
{
    __shared__ unsigned short MHI[8192], MLO[8192], HHI[8192], HLO[8192];
    const int tid = threadIdx.x;
    const int w = tid >> 6, lane = tid & 63, c = lane & 15, g = lane >> 4;
    const long node0 = (long)blockIdx.x * MBLK;
    const int j = w * 16 + c;

    const float bR  = gbih[j] + gbhh[j];
    const float bZ  = gbih[64 + j] + gbhh[64 + j];
    const float bNI = gbih[128 + j];
    const float bNH = gbhh[128 + j];
    const float bL1 = l1b[j];
    const float bL0 = l0b[j];

    const int koff = ((j >> 5) * 512) + (((j >> 3) & 3) * 128) + (j & 7);

    const bf8* WH = (const bf8*)whi;
    const bf8* WL = (const bf8*)wlo;
#define LF(name, jt) \
    bf8 name##h0 = WH[((jt) * 2 + 0) * 64 + lane], name##h1 = WH[((jt) * 2 + 1) * 64 + lane], \
        name##l0 = WL[((jt) * 2 + 0) * 64 + lane], name##l1 = WL[((jt) * 2 + 1) * 64 + lane];
    LF(w0, w)
    LF(w1, 4 + w)
    LF(gir, 8 + w)  LF(giz, 12 + w)  LF(gin, 16 + w)
    LF(ghr, 20 + w) LF(ghz, 24 + w) LF(ghn, 28 + w)
#undef LF

    float hc[TILES][4];

    // ---- lin0 ----
#pragma unroll
    for (int t = 0; t < TILES; ++t) {
        long nd = node0 + t * 16 + c;
        if (nd >= n_nodes) nd = n_nodes - 1;
        const float* xp = x + nd * 64 + g * 8;
        float va[8], vb[8];
        {
            float4 u0 = *(const float4*)xp;
            float4 u1 = *(const float4*)(xp + 4);
            float4 u2 = *(const float4*)(xp + 32);
            float4 u3 = *(const float4*)(xp + 36);
            va[0] = u0.x; va[1] = u0.y; va[2] = u0.z; va[3] = u0.w;
            va[4] = u1.x; va[5] = u1.y; va[6] = u1.z; va[7] = u1.w;
            vb[0] = u2.x; vb[1] = u2.y; vb[2] = u2.z; vb[3] = u2.w;
            vb[4] = u3.x; vb[5] = u3.y; vb[6] = u3.z; vb[7] = u3.w;
        }
        bf8 xh0, xl0, xh1, xl1;
#pragma unroll
        for (int e = 0; e < 8; ++e) {
            unsigned short h0 = f2bf(va[e]);
            xh0[e] = (short)h0; xl0[e] = (short)f2bf(va[e] - bf2f(h0));
            unsigned short h1 = f2bf(vb[e]);
            xh1[e] = (short)h1; xl1[e] = (short)f2bf(vb[e] - bf2f(h1));
        }
        f32x4 acc = {bL0, bL0, bL0, bL0};
        acc = MFMA(xh0, w0h0, acc); acc = MFMA(xl0, w0h0, acc); acc = MFMA(xh0, w0l0, acc);
        acc = MFMA(xh1, w0h1, acc); acc = MFMA(xl1, w0h1, acc); acc = MFMA(xh1, w0l1, acc);
#pragma unroll
        for (int p = 0; p < 4; ++p) {
            float hv = fmaxf(acc[p], 0.0f);
            hc[t][p] = hv;
            int r = g * 4 + p;
            unsigned short hi = f2bf(hv);
            HHI[t * 1024 + koff + r * 8] = hi;
            HLO[t * 1024 + koff + r * 8] = f2bf(hv - bf2f(hi));
        }
    }
    __syncthreads();

    for (int iter = 0; iter < 3; ++iter) {
        // ---- lin1 ----
#pragma unroll
        for (int t = 0; t < TILES; ++t) {
            const bf8* hh = (const bf8*)&HHI[t * 1024];
            const bf8* hl = (const bf8*)&HLO[t * 1024];
            bf8 ah0 = hh[lane], ah1 = hh[64 + lane];
            bf8 al0 = hl[lane], al1 = hl[64 + lane];
            f32x4 acc = {bL1, bL1, bL1, bL1};
            acc = MFMA(ah0, w1h0, acc); acc = MFMA(al0, w1h0, acc); acc = MFMA(ah0, w1l0, acc);
            acc = MFMA(ah1, w1h1, acc); acc = MFMA(al1, w1h1, acc); acc = MFMA(ah1, w1l1, acc);
#pragma unroll
            for (int p = 0; p < 4; ++p) {
                float mv = fmaxf(acc[p], 0.0f);
                int r = g * 4 + p;
                unsigned short hi = f2bf(mv);
                MHI[t * 1024 + koff + r * 8] = hi;
                MLO[t * 1024 + koff + r * 8] = f2bf(mv - bf2f(hi));
            }
        }
        __syncthreads();

        // ---- GRU gates ----
#pragma unroll
        for (int t = 0; t < TILES; ++t) {
            const bf8* mh = (const bf8*)&MHI[t * 1024];
            const bf8* ml = (const bf8*)&MLO[t * 1024];
            const bf8* hh = (const bf8*)&HHI[t * 1024];
            const bf8* hl = (const bf8*)&HLO[t * 1024];
            bf8 amh0 = mh[lane], amh1 = mh[64 + lane];
            bf8 aml0 = ml[lane], aml1 = ml[64 + lane];
            bf8 ahh0 = hh[lane], ahh1 = hh[64 + lane];
            bf8 ahl0 = hl[lane], ahl1 = hl[64 + lane];

            f32x4 aR  = {bR, bR, bR, bR};
            f32x4 aZ  = {bZ, bZ, bZ, bZ};
            f32x4 aNI = {bNI, bNI, bNI, bNI};
            f32x4 aNH = {bNH, bNH, bNH, bNH};

            aR = MFMA(amh0, girh0, aR); aR = MFMA(aml0, girh0, aR); aR = MFMA(amh0, girl0, aR);
            aR = MFMA(amh1, girh1, aR); aR = MFMA(aml1, girh1, aR); aR = MFMA(amh1, girl1, aR);
            aR = MFMA(ahh0, ghrh0, aR); aR = MFMA(ahl0, ghrh0, aR); aR = MFMA(ahh0, ghrl0, aR);
            aR = MFMA(ahh1, ghrh1, aR); aR = MFMA(ahl1, ghrh1, aR); aR = MFMA(ahh1, ghrl1, aR);

            aZ = MFMA(amh0, gizh0, aZ); aZ = MFMA(aml0, gizh0, aZ); aZ = MFMA(amh0, gizl0, aZ);
            aZ = MFMA(amh1, gizh1, aZ); aZ = MFMA(aml1, gizh1, aZ); aZ = MFMA(amh1, gizl1, aZ);
            aZ = MFMA(ahh0, ghzh0, aZ); aZ = MFMA(ahl0, ghzh0, aZ); aZ = MFMA(ahh0, ghzl0, aZ);
            aZ = MFMA(ahh1, ghzh1, aZ); aZ = MFMA(ahl1, ghzh1, aZ); aZ = MFMA(ahh1, ghzl1, aZ);

            aNI = MFMA(amh0, ginh0, aNI); aNI = MFMA(aml0, ginh0, aNI); aNI = MFMA(amh0, ginl0, aNI);
            aNI = MFMA(amh1, ginh1, aNI); aNI = MFMA(aml1, ginh1, aNI); aNI = MFMA(amh1, ginl1, aNI);

            aNH = MFMA(ahh0, ghnh0, aNH); aNH = MFMA(ahl0, ghnh0, aNH); aNH = MFMA(ahh0, ghnl0, aNH);
            aNH = MFMA(ahh1, ghnh1, aNH); aNH = MFMA(ahl1, ghnh1, aNH); aNH = MFMA(ahh1, ghnl1, aNH);

#pragma unroll
            for (int p = 0; p < 4; ++p) {
                float rg = sigm(aR[p]);
                float zg = sigm(aZ[p]);
                float ng = tanh2(aNI[p] + rg * aNH[p]);
                hc[t][p] = (1.0f - zg) * ng + zg * hc[t][p];
            }
        }

        if (iter < 2) {
            __syncthreads();
#pragma unroll
            for (int t = 0; t < TILES; ++t)
#pragma unroll
                for (int p = 0; p < 4; ++p) {
                    int r = g * 4 + p;
                    unsigned short hi = f2bf(hc[t][p]);
                    HHI[t * 1024 + koff + r * 8] = hi;
                    HLO[t * 1024 + koff + r * 8] = f2bf(hc[t][p] - bf2f(hi));
                }
            __syncthreads();
        }
    }

#pragma unroll
    for (int t = 0; t < TILES; ++t)
#pragma unroll
        for (int p = 0; p < 4; ++p) {
            long nd = node0 + t * 16 + g * 4 + p;
            if (nd < n_nodes) outv[nd * 64 + j] = hc[t][p];
        }
}

// ---------------------------------------------------------------------------
// Set2Set (3 steps) + head. Block = 1 graph. Node features staged ONCE into
// LDS (d-major, stride NP=193: pass-1 reads conflict-free, pass-3 2-way).
// Global fallback for segments > MAXN nodes (correctness only; never hot).
// ---------------------------------------------------------------------------
__device__ __forceinline__ float blk_max(float v, float* redm, int t) {
#pragma unroll
    for (int o = 32; o > 0; o >>= 1) v = fmaxf(v, __shfl_xor(v, o));
    __syncthreads();
    if ((t & 63) == 0) redm[t >> 6] = v;
    __syncthreads();
    return fmaxf(fmaxf(redm[0], redm[1]), fmaxf(redm[2], redm[3]));
}
__device__ __forceinline__ float blk_sum(float v, float* redm, int t) {
#pragma unroll
    for (int o = 32; o > 0; o >>= 1) v += __shfl_xor(v, o);
    __syncthreads();
    if ((t & 63) == 0) redm[t >> 6] = v;
    __syncthreads();
    return (redm[0] + redm[1]) + (redm[2] + redm[3]);
}
__device__ __forceinline__ float node_dot(const float* __restrict__ outv, long row,
                                          const float* q) {
    const float4* rp = (const float4*)(outv + row * 64);
    float e = 0.0f;
#pragma unroll
    for (int u = 0; u < 16; ++u) {
        float4 v = rp[u];
        e = fmaf(v.x, q[4 * u + 0], e);
        e = fmaf(v.y, q[4 * u + 1], e);
        e = fmaf(v.z, q[4 * u + 2], e);
        e = fmaf(v.w, q[4 * u + 3], e);
    }
    return e;
}

__global__ void s2s_kernel(const float* __restrict__ outv,
                           const int* __restrict__ startp,
                           const float* __restrict__ liT, const float* __restrict__ lhT,
                           const float* __restrict__ lbih, const float* __restrict__ lbhh,
                           const float* __restrict__ l2w, const float* __restrict__ l2b,
                           const float* __restrict__ l3w, const float* __restrict__ l3b,
                           float* __restrict__ yout)
{
    __shared__ float featT[64 * NP];   // 49408 B, d-major
    __shared__ float qstarS[128];
    __shared__ float hlS[64];
    __shared__ float clS[64];
    __shared__ float gbuf[256];        // LSTM gates (phase A) / pass-3 partials (phase B)
    __shared__ float eS[MAXN];
    __shared__ float redm[4];

    const int g = blockIdx.x;
    const int t = threadIdx.x;
    const int s0 = startp[g];
    const int cnt = startp[g + 1] - s0;
    const int nst = cnt < MAXN ? cnt : MAXN;

    // ---- stage segment features into LDS (read outv exactly once) ----
    for (int i = t; i < nst * 16; i += TS) {
        int n = i >> 4, dc = (i & 15) * 4;
        float4 v = *(const float4*)(outv + (long)(s0 + n) * 64 + dc);
        featT[(dc + 0) * NP + n] = v.x;
        featT[(dc + 1) * NP + n] = v.y;
        featT[(dc + 2) * NP + n] = v.z;
        featT[(dc + 3) * NP + n] = v.w;
    }
    if (t < 128) qstarS[t] = 0.0f;
    if (t < 64) { hlS[t] = 0.0f; clS[t] = 0.0f; }
    __syncthreads();

    for (int step = 0; step < 3; ++step) {
        // LSTM gates: thread t = gate row; 4 accumulators break the dep chain
        {
            float a0 = lbih[t] + lbhh[t], a1 = 0.0f, a2 = 0.0f, a3 = 0.0f;
            for (int k = 0; k < 128; k += 4) {
                a0 = fmaf(liT[(k + 0) * 256 + t], qstarS[k + 0], a0);
                a1 = fmaf(liT[(k + 1) * 256 + t], qstarS[k + 1], a1);
                a2 = fmaf(liT[(k + 2) * 256 + t], qstarS[k + 2], a2);
                a3 = fmaf(liT[(k + 3) * 256 + t], qstarS[k + 3], a3);
            }
            for (int k = 0; k < 64; k += 4) {
                a0 = fmaf(lhT[(k + 0) * 256 + t], hlS[k + 0], a0);
                a1 = fmaf(lhT[(k + 1) * 256 + t], hlS[k + 1], a1);
                a2 = fmaf(lhT[(k + 2) * 256 + t], hlS[k + 2], a2);
                a3 = fmaf(lhT[(k + 3) * 256 + t], hlS[k + 3], a3);
            }
            gbuf[t] = (a0 + a1) + (a2 + a3);
        }
        __syncthreads();
        if (t < 64) {
            float c = sigm(gbuf[64 + t]) * clS[t] + sigm(gbuf[t]) * tanh2(gbuf[128 + t]);
            clS[t] = c;
            hlS[t] = sigm(gbuf[192 + t]) * tanh2(c);  // q = hl
        }
        __syncthreads();

        // pass 1: e_n = <feat_n, q>, segment max
        float lmax = -INFINITY;
        for (int n = t; n < cnt; n += TS) {
            float e;
            if (n < MAXN) {
                float e0 = 0.0f, e1 = 0.0f, e2 = 0.0f, e3 = 0.0f;
#pragma unroll
                for (int d = 0; d < 64; d += 4) {
                    e0 = fmaf(featT[(d + 0) * NP + n], hlS[d + 0], e0);
                    e1 = fmaf(featT[(d + 1) * NP + n], hlS[d + 1], e1);
                    e2 = fmaf(featT[(d + 2) * NP + n], hlS[d + 2], e2);
                    e3 = fmaf(featT[(d + 3) * NP + n], hlS[d + 3], e3);
                }
                e = (e0 + e1) + (e2 + e3);
                eS[n] = e;
            } else {
                e = node_dot(outv, (long)(s0 + n), hlS);
            }
            lmax = fmaxf(lmax, e);
        }
        float mval = blk_max(lmax, redm, t);   // barriers make eS visible

        // pass 2: sum of exp (exp stored back to eS)
        float lsum = 0.0f;
        for (int n = t; n < cnt; n += TS) {
            float e = (n < MAXN) ? eS[n] : node_dot(outv, (long)(s0 + n), hlS);
            float ex = __expf(e - mval);
            lsum += ex;
            if (n < MAXN) eS[n] = ex;
        }
        float sval = blk_sum(lsum, redm, t);

        // pass 3: r_d = sum_n exp_n * feat[d][n]
        float racc = 0.0f;
        {
            const int d = t & 63;
            const int q4 = t >> 6;
            for (int n = q4; n < nst; n += 4)
                racc = fmaf(eS[n], featT[d * NP + n], racc);
            if (cnt > MAXN && t < 64) {        // generic overflow path
                for (int n = MAXN; n < cnt; ++n) {
                    float e = outv[(long)(s0 + n) * 64 + t] * hlS[t];
#pragma unroll
                    for (int o = 32; o > 0; o >>= 1) e += __shfl_xor(e, o);
                    float ex = __expf(e - mval);
                    racc = fmaf(ex, outv[(long)(s0 + n) * 64 + t], racc);
                }
            }
        }
        __syncthreads();                       // gbuf free (LSTM phase done)
        gbuf[t] = racc;
        __syncthreads();
        if (t < 64) {
            float r = (gbuf[t] + gbuf[64 + t]) + (gbuf[128 + t] + gbuf[192 + t]);
            qstarS[t] = hlS[t];
            qstarS[64 + t] = r / (sval + 1e-16f);
        }
        __syncthreads();
    }

    // head: y = relu(lin2(qstar)); out = lin3(y)
    if (t < 64) {
        float acc = l2b[t];
        for (int k = 0; k < 128; ++k) acc = fmaf(l2w[t * 128 + k], qstarS[k], acc);
        gbuf[t] = fmaxf(acc, 0.0f);
    }
    __syncthreads();
    if (t < 64) {
        float p = l3w[t] * gbuf[t];
#pragma unroll
        for (int o = 32; o > 0; o >>= 1) p += __shfl_xor(p, o);
        if (t == 0) yout[g] = p + l3b[0];
    }
}

// ---------------------------------------------------------------------------
extern "C" void kernel_launch(void* const* d_in, const int* in_sizes, int n_in,
                              void* d_out, int out_size, void* d_ws, size_t ws_size,
                              hipStream_t stream)
{
    const float* x     = (const float*)d_in[0];
    const int*   batch = (const int*)d_in[1];
    const float* l0w   = (const float*)d_in[2];
    const float* l0b   = (const float*)d_in[3];
    const float* l1w   = (const float*)d_in[4];
    const float* l1b   = (const float*)d_in[5];
    const float* gwih  = (const float*)d_in[6];
    const float* gwhh  = (const float*)d_in[7];
    const float* gbih  = (const float*)d_in[8];
    const float* gbhh  = (const float*)d_in[9];
    const float* lwih  = (const float*)d_in[10];
    const float* lwhh  = (const float*)d_in[11];
    const float* lbih  = (const float*)d_in[12];
    const float* lbhh  = (const float*)d_in[13];
    const float* l2w   = (const float*)d_in[14];
    const float* l2b   = (const float*)d_in[15];
    const float* l3w   = (const float*)d_in[16];
    const float* l3b   = (const float*)d_in[17];

    const int n_nodes  = in_sizes[1];
    const int n_graphs = out_size;

    float* wsf = (float*)d_ws;
    float* outv = wsf;                                    // n_nodes*64 f32
    float* liT  = wsf + (size_t)n_nodes * 64;             // 32768 f32
    float* lhT  = liT + 32768;                            // 16384 f32
    unsigned short* whi = (unsigned short*)(lhT + 16384); // 32768 u16
    unsigned short* wlo = whi + 32768;                    // 32768 u16
    int* startp = (int*)(wlo + 32768);                    // n_graphs+1

    prep_kernel<<<128, 256, 0, stream>>>(l0w, l1w, gwih, gwhh, lwih, lwhh, batch,
                                         whi, wlo, liT, lhT, startp, n_nodes, n_graphs);
    node_kernel<<<(n_nodes + MBLK - 1) / MBLK, 256, 0, stream>>>(
        x, whi, wlo, l0b, l1b, gbih, gbhh, outv, n_nodes);
    s2s_kernel<<<n_graphs, TS, 0, stream>>>(outv, startp, liT, lhT,
                                            lbih, lbhh, l2w, l2b, l3w, l3b,
                                            (float*)d_out);
}

// Round 5
// 853.925 us; speedup vs baseline: 2.3037x; 2.3037x over previous
//
#include <hip/hip_runtime.h>
#include <hip/hip_bf16.h>
#include <math.h>

#define TILES 8
#define MBLK 128

typedef __attribute__((ext_vector_type(8))) short bf8;
typedef __attribute__((ext_vector_type(4))) float f32x4;

#define MFMA(a, b, c) __builtin_amdgcn_mfma_f32_16x16x32_bf16(a, b, c, 0, 0, 0)

__device__ __forceinline__ float fast_rcp(float x) { return __builtin_amdgcn_rcpf(x); }
__device__ __forceinline__ float sigm(float x) { return fast_rcp(1.0f + __expf(-x)); }
__device__ __forceinline__ float tanh2(float x) { return fmaf(2.0f, fast_rcp(1.0f + __expf(-2.0f * x)), -1.0f); }

__device__ __forceinline__ unsigned short f2bf(float v) {
    union { __hip_bfloat16 b; unsigned short u; } cv;
    cv.b = __float2bfloat16(v);
    return cv.u;
}
__device__ __forceinline__ float bf2f(unsigned short u) {
    union { unsigned short u; __hip_bfloat16 b; } cv;
    cv.u = u;
    return __bfloat162float(cv.b);
}
__device__ __forceinline__ f32x4 ntload4(const float* p) {
    return __builtin_nontemporal_load((const f32x4*)p);
}

// ---------------------------------------------------------------------------
// prep: node-weight split-bf16 B-frags, LSTM weight transposes, l2 transpose,
// segment starts, and zero-init of s2s state (u, cl) for determinism.
// ---------------------------------------------------------------------------
__global__ void prep_kernel(const float* __restrict__ l0w, const float* __restrict__ l1w,
                            const float* __restrict__ gwih, const float* __restrict__ gwhh,
                            const float* __restrict__ lwih, const float* __restrict__ lwhh,
                            const float* __restrict__ l2w,
                            const int* __restrict__ batch,
                            unsigned short* __restrict__ whi, unsigned short* __restrict__ wlo,
                            float* __restrict__ liT, float* __restrict__ lhT,
                            float* __restrict__ l2T,
                            float* __restrict__ u, float* __restrict__ cl,
                            int* __restrict__ startp,
                            int n_nodes, int n_graphs)
{
    int tid = blockIdx.x * 256 + threadIdx.x;
    int nthreads = gridDim.x * 256;
    if (tid < 32768) {
        int e = tid & 7, lane = (tid >> 3) & 63, ks = (tid >> 9) & 1, jt = tid >> 10;
        const float* W; int jl;
        if (jt < 4)       { W = l0w;  jl = jt; }
        else if (jt < 8)  { W = l1w;  jl = jt - 4; }
        else if (jt < 20) { W = gwih; jl = jt - 8; }
        else              { W = gwhh; jl = jt - 20; }
        int j = jl * 16 + (lane & 15);
        int k = ks * 32 + (lane >> 4) * 8 + e;
        float v = W[j * 64 + k];
        unsigned short hi = f2bf(v);
        whi[tid] = hi;
        wlo[tid] = f2bf(v - bf2f(hi));
    }
    if (tid < 32768) liT[tid] = lwih[(tid & 255) * 128 + (tid >> 8)];  // liT[k*256+j]
    if (tid < 16384) lhT[tid] = lwhh[(tid & 255) * 64 + (tid >> 8)];   // lhT[k*256+j]
    if (tid < 8192)  l2T[tid] = l2w[(tid & 63) * 128 + (tid >> 6)];    // l2T[k*64+d]
    if (tid <= n_graphs) {
        int lo = 0, hi = n_nodes;
        while (lo < hi) {
            int mid = (lo + hi) >> 1;
            if (batch[mid] < tid) lo = mid + 1; else hi = mid;
        }
        startp[tid] = lo;
    }
    // zero s2s state
    for (int i = tid; i < n_graphs * 192; i += nthreads) u[i] = 0.0f;
    for (int i = tid; i < n_graphs * 64;  i += nthreads) cl[i] = 0.0f;
}

// ---------------------------------------------------------------------------
// node pipeline via split-bf16 MFMA (unchanged from round 2)
// ---------------------------------------------------------------------------
__launch_bounds__(256, 2)
__global__ void node_kernel(const float* __restrict__ x,
                            const unsigned short* __restrict__ whi,
                            const unsigned short* __restrict__ wlo,
                            const float* __restrict__ l0b, const float* __restrict__ l1b,
                            const float* __restrict__ gbih, const float* __restrict__ gbhh,
                            float* __restrict__ outv, int n_nodes)
{
    __shared__ unsigned short MHI[8192], MLO[8192], HHI[8192], HLO[8192];
    const int tid = threadIdx.x;
    const int w = tid >> 6, lane = tid & 63, c = lane & 15, g = lane >> 4;
    const long node0 = (long)blockIdx.x * MBLK;
    const int j = w * 16 + c;

    const float bR  = gbih[j] + gbhh[j];
    const float bZ  = gbih[64 + j] + gbhh[64 + j];
    const float bNI = gbih[128 + j];
    const float bNH = gbhh[128 + j];
    const float bL1 = l1b[j];
    const float bL0 = l0b[j];

    const int koff = ((j >> 5) * 512) + (((j >> 3) & 3) * 128) + (j & 7);

    const bf8* WH = (const bf8*)whi;
    const bf8* WL = (const bf8*)wlo;
#define LF(name, jt) \
    bf8 name##h0 = WH[((jt) * 2 + 0) * 64 + lane], name##h1 = WH[((jt) * 2 + 1) * 64 + lane], \
        name##l0 = WL[((jt) * 2 + 0) * 64 + lane], name##l1 = WL[((jt) * 2 + 1) * 64 + lane];
    LF(w0, w)
    LF(w1, 4 + w)
    LF(gir, 8 + w)  LF(giz, 12 + w)  LF(gin, 16 + w)
    LF(ghr, 20 + w) LF(ghz, 24 + w) LF(ghn, 28 + w)
#undef LF

    float hc[TILES][4];

    // ---- lin0 ----
#pragma unroll
    for (int t = 0; t < TILES; ++t) {
        long nd = node0 + t * 16 + c;
        if (nd >= n_nodes) nd = n_nodes - 1;
        const float* xp = x + nd * 64 + g * 8;
        float va[8], vb[8];
        {
            float4 u0 = *(const float4*)xp;
            float4 u1 = *(const float4*)(xp + 4);
            float4 u2 = *(const float4*)(xp + 32);
            float4 u3 = *(const float4*)(xp + 36);
            va[0] = u0.x; va[1] = u0.y; va[2] = u0.z; va[3] = u0.w;
            va[4] = u1.x; va[5] = u1.y; va[6] = u1.z; va[7] = u1.w;
            vb[0] = u2.x; vb[1] = u2.y; vb[2] = u2.z; vb[3] = u2.w;
            vb[4] = u3.x; vb[5] = u3.y; vb[6] = u3.z; vb[7] = u3.w;
        }
        bf8 xh0, xl0, xh1, xl1;
#pragma unroll
        for (int e = 0; e < 8; ++e) {
            unsigned short h0 = f2bf(va[e]);
            xh0[e] = (short)h0; xl0[e] = (short)f2bf(va[e] - bf2f(h0));
            unsigned short h1 = f2bf(vb[e]);
            xh1[e] = (short)h1; xl1[e] = (short)f2bf(vb[e] - bf2f(h1));
        }
        f32x4 acc = {bL0, bL0, bL0, bL0};
        acc = MFMA(xh0, w0h0, acc); acc = MFMA(xl0, w0h0, acc); acc = MFMA(xh0, w0l0, acc);
        acc = MFMA(xh1, w0h1, acc); acc = MFMA(xl1, w0h1, acc); acc = MFMA(xh1, w0l1, acc);
#pragma unroll
        for (int p = 0; p < 4; ++p) {
            float hv = fmaxf(acc[p], 0.0f);
            hc[t][p] = hv;
            int r = g * 4 + p;
            unsigned short hi = f2bf(hv);
            HHI[t * 1024 + koff + r * 8] = hi;
            HLO[t * 1024 + koff + r * 8] = f2bf(hv - bf2f(hi));
        }
    }
    __syncthreads();

    for (int iter = 0; iter < 3; ++iter) {
        // ---- lin1 ----
#pragma unroll
        for (int t = 0; t < TILES; ++t) {
            const bf8* hh = (const bf8*)&HHI[t * 1024];
            const bf8* hl = (const bf8*)&HLO[t * 1024];
            bf8 ah0 = hh[lane], ah1 = hh[64 + lane];
            bf8 al0 = hl[lane], al1 = hl[64 + lane];
            f32x4 acc = {bL1, bL1, bL1, bL1};
            acc = MFMA(ah0, w1h0, acc); acc = MFMA(al0, w1h0, acc); acc = MFMA(ah0, w1l0, acc);
            acc = MFMA(ah1, w1h1, acc); acc = MFMA(al1, w1h1, acc); acc = MFMA(ah1, w1l1, acc);
#pragma unroll
            for (int p = 0; p < 4; ++p) {
                float mv = fmaxf(acc[p], 0.0f);
                int r = g * 4 + p;
                unsigned short hi = f2bf(mv);
                MHI[t * 1024 + koff + r * 8] = hi;
                MLO[t * 1024 + koff + r * 8] = f2bf(mv - bf2f(hi));
            }
        }
        __syncthreads();

        // ---- GRU gates ----
#pragma unroll
        for (int t = 0; t < TILES; ++t) {
            const bf8* mh = (const bf8*)&MHI[t * 1024];
            const bf8* ml = (const bf8*)&MLO[t * 1024];
            const bf8* hh = (const bf8*)&HHI[t * 1024];
            const bf8* hl = (const bf8*)&HLO[t * 1024];
            bf8 amh0 = mh[lane], amh1 = mh[64 + lane];
            bf8 aml0 = ml[lane], aml1 = ml[64 + lane];
            bf8 ahh0 = hh[lane], ahh1 = hh[64 + lane];
            bf8 ahl0 = hl[lane], ahl1 = hl[64 + lane];

            f32x4 aR  = {bR, bR, bR, bR};
            f32x4 aZ  = {bZ, bZ, bZ, bZ};
            f32x4 aNI = {bNI, bNI, bNI, bNI};
            f32x4 aNH = {bNH, bNH, bNH, bNH};

            aR = MFMA(amh0, girh0, aR); aR = MFMA(aml0, girh0, aR); aR = MFMA(amh0, girl0, aR);
            aR = MFMA(amh1, girh1, aR); aR = MFMA(aml1, girh1, aR); aR = MFMA(amh1, girl1, aR);
            aR = MFMA(ahh0, ghrh0, aR); aR = MFMA(ahl0, ghrh0, aR); aR = MFMA(ahh0, ghrl0, aR);
            aR = MFMA(ahh1, ghrh1, aR); aR = MFMA(ahl1, ghrh1, aR); aR = MFMA(ahh1, ghrl1, aR);

            aZ = MFMA(amh0, gizh0, aZ); aZ = MFMA(aml0, gizh0, aZ); aZ = MFMA(amh0, gizl0, aZ);
            aZ = MFMA(amh1, gizh1, aZ); aZ = MFMA(aml1, gizh1, aZ); aZ = MFMA(amh1, gizl1, aZ);
            aZ = MFMA(ahh0, ghzh0, aZ); aZ = MFMA(ahl0, ghzh0, aZ); aZ = MFMA(ahh0, ghzl0, aZ);
            aZ = MFMA(ahh1, ghzh1, aZ); aZ = MFMA(ahl1, ghzh1, aZ); aZ = MFMA(ahh1, ghzl1, aZ);

            aNI = MFMA(amh0, ginh0, aNI); aNI = MFMA(aml0, ginh0, aNI); aNI = MFMA(amh0, ginl0, aNI);
            aNI = MFMA(amh1, ginh1, aNI); aNI = MFMA(aml1, ginh1, aNI); aNI = MFMA(amh1, ginl1, aNI);

            aNH = MFMA(ahh0, ghnh0, aNH); aNH = MFMA(ahl0, ghnh0, aNH); aNH = MFMA(ahh0, ghnl0, aNH);
            aNH = MFMA(ahh1, ghnh1, aNH); aNH = MFMA(ahl1, ghnh1, aNH); aNH = MFMA(ahh1, ghnl1, aNH);

#pragma unroll
            for (int p = 0; p < 4; ++p) {
                float rg = sigm(aR[p]);
                float zg = sigm(aZ[p]);
                float ng = tanh2(aNI[p] + rg * aNH[p]);
                hc[t][p] = (1.0f - zg) * ng + zg * hc[t][p];
            }
        }

        if (iter < 2) {
            __syncthreads();
#pragma unroll
            for (int t = 0; t < TILES; ++t)
#pragma unroll
                for (int p = 0; p < 4; ++p) {
                    int r = g * 4 + p;
                    unsigned short hi = f2bf(hc[t][p]);
                    HHI[t * 1024 + koff + r * 8] = hi;
                    HLO[t * 1024 + koff + r * 8] = f2bf(hc[t][p] - bf2f(hi));
                }
            __syncthreads();
        }
    }

#pragma unroll
    for (int t = 0; t < TILES; ++t)
#pragma unroll
        for (int p = 0; p < 4; ++p) {
            long nd = node0 + t * 16 + g * 4 + p;
            if (nd < n_nodes) outv[nd * 64 + j] = hc[t][p];
        }
}

// ---------------------------------------------------------------------------
// LSTM step, batched over graphs. Wave = 1 graph, lane = channel d.
// u layout per graph: [0:64) q, [64:128) r, [128:192) hl  (q_star = u[0:128)).
// ---------------------------------------------------------------------------
__global__ void lstm_kernel(const float* __restrict__ liT, const float* __restrict__ lhT,
                            const float* __restrict__ lbih, const float* __restrict__ lbhh,
                            float* __restrict__ u, float* __restrict__ cl, int n_graphs)
{
    const int t = threadIdx.x;
    const int g = blockIdx.x * 4 + (t >> 6);
    const int d = t & 63;
    if (g >= n_graphs) return;
    float* ug = u + (size_t)g * 192;

    float aI = lbih[d]       + lbhh[d];
    float aF = lbih[64 + d]  + lbhh[64 + d];
    float aG = lbih[128 + d] + lbhh[128 + d];
    float aO = lbih[192 + d] + lbhh[192 + d];
    for (int k = 0; k < 128; ++k) {
        float uv = ug[k];
        const float* wr = liT + k * 256;
        aI = fmaf(wr[d], uv, aI);
        aF = fmaf(wr[64 + d], uv, aF);
        aG = fmaf(wr[128 + d], uv, aG);
        aO = fmaf(wr[192 + d], uv, aO);
    }
    for (int k = 0; k < 64; ++k) {
        float hv = ug[128 + k];
        const float* wr = lhT + k * 256;
        aI = fmaf(wr[d], hv, aI);
        aF = fmaf(wr[64 + d], hv, aF);
        aG = fmaf(wr[128 + d], hv, aG);
        aO = fmaf(wr[192 + d], hv, aO);
    }
    // all u reads above precede these writes in wave program order
    float c = sigm(aF) * cl[(size_t)g * 64 + d] + sigm(aI) * tanh2(aG);
    cl[(size_t)g * 64 + d] = c;
    float h = sigm(aO) * tanh2(c);
    ug[d] = h;        // q
    ug[128 + d] = h;  // hl
}

// ---------------------------------------------------------------------------
// Attention pass: one block per graph, SINGLE online-softmax pass over the
// segment. 16-lane groups each own every-16th node; lane owns 4 channels.
// outv read exactly once per step (non-temporal). Writes r into u[g][64:128).
// ---------------------------------------------------------------------------
__global__ void attn_kernel(const float* __restrict__ outv,
                            const int* __restrict__ startp,
                            float* __restrict__ u, int n_graphs)
{
    __shared__ float qS[64];
    __shared__ float mG[16], sG[16];
    __shared__ float rG[16][64];

    const int g = blockIdx.x;
    const int t = threadIdx.x;
    const int s0 = startp[g];
    const int cnt = startp[g + 1] - s0;
    if (t < 64) qS[t] = u[(size_t)g * 192 + t];
    __syncthreads();

    const int grp = t >> 4, l = t & 15;
    const float q0 = qS[l * 4], q1 = qS[l * 4 + 1], q2 = qS[l * 4 + 2], q3 = qS[l * 4 + 3];

    float m = -INFINITY, s = 0.0f;
    float r0 = 0.0f, r1 = 0.0f, r2 = 0.0f, r3 = 0.0f;

    int n = grp;
    for (; n + 16 < cnt; n += 32) {   // 2 nodes per iter for VMEM ILP
        f32x4 va = ntload4(outv + (size_t)(s0 + n) * 64 + l * 4);
        f32x4 vb = ntload4(outv + (size_t)(s0 + n + 16) * 64 + l * 4);
        float ea = fmaf(va.x, q0, fmaf(va.y, q1, fmaf(va.z, q2, va.w * q3)));
        float eb = fmaf(vb.x, q0, fmaf(vb.y, q1, fmaf(vb.z, q2, vb.w * q3)));
#pragma unroll
        for (int o = 1; o < 16; o <<= 1) {
            ea += __shfl_xor(ea, o);
            eb += __shfl_xor(eb, o);
        }
        float mn = fmaxf(m, fmaxf(ea, eb));
        float sc = __expf(m - mn);
        float wa = __expf(ea - mn);
        float wb = __expf(eb - mn);
        s = s * sc + wa + wb;
        r0 = fmaf(r0, sc, fmaf(wa, va.x, wb * vb.x));
        r1 = fmaf(r1, sc, fmaf(wa, va.y, wb * vb.y));
        r2 = fmaf(r2, sc, fmaf(wa, va.z, wb * vb.z));
        r3 = fmaf(r3, sc, fmaf(wa, va.w, wb * vb.w));
        m = mn;
    }
    if (n < cnt) {
        f32x4 va = ntload4(outv + (size_t)(s0 + n) * 64 + l * 4);
        float ea = fmaf(va.x, q0, fmaf(va.y, q1, fmaf(va.z, q2, va.w * q3)));
#pragma unroll
        for (int o = 1; o < 16; o <<= 1) ea += __shfl_xor(ea, o);
        float mn = fmaxf(m, ea);
        float sc = __expf(m - mn);
        float wa = __expf(ea - mn);
        s = s * sc + wa;
        r0 = fmaf(r0, sc, wa * va.x);
        r1 = fmaf(r1, sc, wa * va.y);
        r2 = fmaf(r2, sc, wa * va.z);
        r3 = fmaf(r3, sc, wa * va.w);
        m = mn;
    }

    if (l == 0) { mG[grp] = m; sG[grp] = s; }
    rG[grp][l * 4 + 0] = r0;
    rG[grp][l * 4 + 1] = r1;
    rG[grp][l * 4 + 2] = r2;
    rG[grp][l * 4 + 3] = r3;
    __syncthreads();

    if (t < 64) {
        float M = -INFINITY;
#pragma unroll
        for (int j2 = 0; j2 < 16; ++j2) M = fmaxf(M, mG[j2]);
        float out;
        if (M == -INFINITY) {
            out = 0.0f;  // empty segment
        } else {
            float ssum = 0.0f, racc = 0.0f;
#pragma unroll
            for (int j2 = 0; j2 < 16; ++j2) {
                float sc = __expf(mG[j2] - M);
                ssum = fmaf(sG[j2], sc, ssum);
                racc = fmaf(rG[j2][t], sc, racc);
            }
            out = racc / (ssum + 1e-16f);
        }
        u[(size_t)g * 192 + 64 + t] = out;
    }
}

// ---------------------------------------------------------------------------
// head: y = lin3(relu(lin2(q_star))). Wave = 1 graph.
// ---------------------------------------------------------------------------
__global__ void head_kernel(const float* __restrict__ u,
                            const float* __restrict__ l2T, const float* __restrict__ l2b,
                            const float* __restrict__ l3w, const float* __restrict__ l3b,
                            float* __restrict__ yout, int n_graphs)
{
    const int t = threadIdx.x;
    const int g = blockIdx.x * 4 + (t >> 6);
    const int d = t & 63;
    if (g >= n_graphs) return;
    const float* ug = u + (size_t)g * 192;  // q_star = [0:128)
    float a0 = l2b[d], a1 = 0.0f, a2 = 0.0f, a3 = 0.0f;
    for (int k = 0; k < 128; k += 4) {
        a0 = fmaf(l2T[(k + 0) * 64 + d], ug[k + 0], a0);
        a1 = fmaf(l2T[(k + 1) * 64 + d], ug[k + 1], a1);
        a2 = fmaf(l2T[(k + 2) * 64 + d], ug[k + 2], a2);
        a3 = fmaf(l2T[(k + 3) * 64 + d], ug[k + 3], a3);
    }
    float y = fmaxf((a0 + a1) + (a2 + a3), 0.0f);
    float p = l3w[d] * y;
#pragma unroll
    for (int o = 32; o > 0; o >>= 1) p += __shfl_xor(p, o);
    if (d == 0) yout[g] = p + l3b[0];
}

// ---------------------------------------------------------------------------
extern "C" void kernel_launch(void* const* d_in, const int* in_sizes, int n_in,
                              void* d_out, int out_size, void* d_ws, size_t ws_size,
                              hipStream_t stream)
{
    const float* x     = (const float*)d_in[0];
    const int*   batch = (const int*)d_in[1];
    const float* l0w   = (const float*)d_in[2];
    const float* l0b   = (const float*)d_in[3];
    const float* l1w   = (const float*)d_in[4];
    const float* l1b   = (const float*)d_in[5];
    const float* gwih  = (const float*)d_in[6];
    const float* gwhh  = (const float*)d_in[7];
    const float* gbih  = (const float*)d_in[8];
    const float* gbhh  = (const float*)d_in[9];
    const float* lwih  = (const float*)d_in[10];
    const float* lwhh  = (const float*)d_in[11];
    const float* lbih  = (const float*)d_in[12];
    const float* lbhh  = (const float*)d_in[13];
    const float* l2w   = (const float*)d_in[14];
    const float* l2b   = (const float*)d_in[15];
    const float* l3w   = (const float*)d_in[16];
    const float* l3b   = (const float*)d_in[17];

    const int n_nodes  = in_sizes[1];
    const int n_graphs = out_size;

    float* wsf = (float*)d_ws;
    float* outv = wsf;                                    // n_nodes*64 f32
    float* liT  = wsf + (size_t)n_nodes * 64;             // 32768 f32
    float* lhT  = liT + 32768;                            // 16384 f32
    float* l2T  = lhT + 16384;                            // 8192 f32
    unsigned short* whi = (unsigned short*)(l2T + 8192);  // 32768 u16
    unsigned short* wlo = whi + 32768;                    // 32768 u16
    float* u    = (float*)(wlo + 32768);                  // n_graphs*192 f32
    float* cl   = u + (size_t)n_graphs * 192;             // n_graphs*64 f32
    int* startp = (int*)(cl + (size_t)n_graphs * 64);     // n_graphs+1

    prep_kernel<<<768, 256, 0, stream>>>(l0w, l1w, gwih, gwhh, lwih, lwhh, l2w, batch,
                                         whi, wlo, liT, lhT, l2T, u, cl, startp,
                                         n_nodes, n_graphs);
    node_kernel<<<(n_nodes + MBLK - 1) / MBLK, 256, 0, stream>>>(
        x, whi, wlo, l0b, l1b, gbih, gbhh, outv, n_nodes);
    for (int step = 0; step < 3; ++step) {
        lstm_kernel<<<(n_graphs + 3) / 4, 256, 0, stream>>>(liT, lhT, lbih, lbhh,
                                                            u, cl, n_graphs);
        attn_kernel<<<n_graphs, 256, 0, stream>>>(outv, startp, u, n_graphs);
    }
    head_kernel<<<(n_graphs + 3) / 4, 256, 0, stream>>>(u, l2T, l2b, l3w, l3b,
                                                        (float*)d_out, n_graphs);
}